// Round 4
// baseline (16038.100 us; speedup 1.0000x reference)
//
#include <hip/hip_runtime.h>

#define NR 4096
#define NT 720
#define TSEC 3600.0f
#define QLB 1e-4f
#define COLS_MAX 32768
#define MAXC 6
#define ROUNDS_MAX 20
#define TAILCAP (ROUNDS_MAX * 64)

// ---------------- CSR build: count ----------------
__global__ void count_kernel(const float* __restrict__ adj, int* __restrict__ cnt) {
    int row = blockIdx.x;
    int lane = threadIdx.x;
    const float* r = adj + (size_t)row * NR;
    int c = 0;
    for (int base = 0; base < NR; base += 64) {
        float v = r[base + lane];
        unsigned long long m = __ballot(v != 0.0f);
        c += __popcll(m);
    }
    if (lane == 0) cnt[row] = c;
}

// ---------------- exclusive scan (single block, 1024 thr, 4/thread) ----------------
__global__ void scan_kernel(const int* __restrict__ cnt, int* __restrict__ rowptr) {
    __shared__ int part[1024];
    int tid = threadIdx.x;
    int base = tid * 4;
    int s0 = cnt[base], s1 = cnt[base + 1], s2 = cnt[base + 2], s3 = cnt[base + 3];
    int tot = s0 + s1 + s2 + s3;
    part[tid] = tot;
    __syncthreads();
    for (int off = 1; off < 1024; off <<= 1) {
        int v = part[tid];
        int add = (tid >= off) ? part[tid - off] : 0;
        __syncthreads();
        part[tid] = v + add;
        __syncthreads();
    }
    int excl = (tid > 0) ? part[tid - 1] : 0;
    rowptr[base]     = excl;
    rowptr[base + 1] = excl + s0;
    rowptr[base + 2] = excl + s0 + s1;
    rowptr[base + 3] = excl + s0 + s1 + s2;
    if (tid == 1023) rowptr[NR] = excl + tot;
}

// ---------------- CSR build: fill ----------------
__global__ void fill_kernel(const float* __restrict__ adj,
                            const int* __restrict__ rowptr, int* __restrict__ cols) {
    int row = blockIdx.x;
    int lane = threadIdx.x;
    const float* r = adj + (size_t)row * NR;
    int wbase = rowptr[row];
    for (int base = 0; base < NR; base += 64) {
        float v = r[base + lane];
        unsigned long long m = __ballot(v != 0.0f);
        if (v != 0.0f) {
            int pos = __popcll(m & ((1ull << lane) - 1ull));
            cols[wbase + pos] = base + lane;
        }
        wbase += __popcll(m);
    }
}

// ---------------- DAG levels (monotone Jacobi to fixpoint) ----------------
__global__ void level_kernel(const int* __restrict__ rowptr,
                             const int* __restrict__ cols, int* __restrict__ level_g) {
    __shared__ int lev[NR];
    __shared__ int changed;
    int tid = threadIdx.x;
#pragma unroll
    for (int k = 0; k < 4; k++) lev[tid + k * 1024] = 0;
    __syncthreads();
    for (int iter = 0; iter < NR; ++iter) {
        if (tid == 0) changed = 0;
        __syncthreads();
#pragma unroll
        for (int k = 0; k < 4; k++) {
            int i = tid + k * 1024;
            int b0 = rowptr[i], b1 = rowptr[i + 1];
            int m = 0;
            for (int e = b0; e < b1; e++) {
                int l = lev[cols[e]] + 1;
                m = (l > m) ? l : m;
            }
            if (b1 > b0 && m != lev[i]) { lev[i] = m; changed = 1; }
        }
        __syncthreads();
        if (changed == 0) break;
        __syncthreads();
    }
#pragma unroll
    for (int k = 0; k < 4; k++) level_g[tid + k * 1024] = lev[tid + k * 1024];
}

// ---------------- level sort: bitonic on (level<<12 | row), deterministic ----------------
__global__ void sort_kernel(const int* __restrict__ level_g, const int* __restrict__ cnt,
                            int* __restrict__ perm, int* __restrict__ inv,
                            int* __restrict__ lev_p, int* __restrict__ cnt_p,
                            int* __restrict__ meta) {
    __shared__ int keys[NR];
    int tid = threadIdx.x;
#pragma unroll
    for (int m = 0; m < 4; m++) {
        int i = tid + m * 1024;
        keys[i] = (level_g[i] << 12) | i;
    }
    __syncthreads();
    for (int ks = 2; ks <= NR; ks <<= 1) {
        for (int j = ks >> 1; j >= 1; j >>= 1) {
#pragma unroll
            for (int m = 0; m < 4; m++) {
                int i = tid + m * 1024;
                int p = i ^ j;
                if (p > i) {
                    bool up = ((i & ks) == 0);
                    int a = keys[i], b = keys[p];
                    if (up ? (a > b) : (a < b)) { keys[i] = b; keys[p] = a; }
                }
            }
            __syncthreads();
        }
    }
#pragma unroll
    for (int m = 0; m < 4; m++) {
        int p = tid + m * 1024;
        int key = keys[p];
        int row = key & (NR - 1);
        perm[p] = row;
        inv[row] = p;
        lev_p[p] = key >> 12;
        cnt_p[p] = cnt[row];
        if (row == NR - 1) meta[1] = p;       // gage sorted position
        if (p == NR - 1) meta[0] = key >> 12; // max level
    }
}

// ---------------- translate cols to sorted index space ----------------
__global__ void trans_kernel(const int* __restrict__ perm, const int* __restrict__ rowptr,
                             const int* __restrict__ cols, const int* __restrict__ inv,
                             const int* __restrict__ rowptr_p, int* __restrict__ cols_p) {
    int pos = blockIdx.x * blockDim.x + threadIdx.x;
    if (pos >= NR) return;
    int row = perm[pos];
    int b0 = rowptr[row];
    int n = rowptr[row + 1] - b0;
    int w = rowptr_p[pos];
    for (int j = 0; j < n; j++) cols_p[w + j] = inv[cols[b0 + j]];
}

// ---------------- coefficients (written in sorted order) ----------------
__global__ void coef_kernel(const int* __restrict__ perm,
                            const float* __restrict__ raw_n,
                            const float* __restrict__ raw_q,
                            const float* __restrict__ raw_p,
                            const float* __restrict__ width,
                            const float* __restrict__ length,
                            const float* __restrict__ slope,
                            const float* __restrict__ x_storage,
                            float* __restrict__ c1, float* __restrict__ c2,
                            float* __restrict__ c3, float* __restrict__ c4) {
    int pos = blockIdx.x * blockDim.x + threadIdx.x;
    if (pos >= NR) return;
    int i = perm[pos];
    float n   = 0.01f + raw_n[i] * (0.3f - 0.01f);
    float qsp = 1.5f + raw_q[i] * (3.0f - 1.5f);
    float psp = 0.5f + raw_p[i] * (2.0f - 0.5f);
    float s0  = fmaxf(slope[i], 1e-4f);
    float depth = logf(width[i] / psp) / logf(qsp);
    float v = (1.0f / n) * powf(depth, 2.0f / 3.0f) * sqrtf(s0);
    float c = fminf(fmaxf(v, 0.3f), 15.0f) * (5.0f / 3.0f);
    float k = length[i] / c;
    float x = x_storage[0];
    float denom = 2.0f * k * (1.0f - x) + TSEC;
    c1[pos] = (TSEC - 2.0f * k * x) / denom;
    c2[pos] = (TSEC + 2.0f * k * x) / denom;
    c3[pos] = (2.0f * k * (1.0f - x) - TSEC) / denom;
    c4[pos] = 2.0f * TSEC / denom;
}

// ---------------- split/round table: pick K, build tail rounds ----------------
__global__ void meta2_kernel(const int* __restrict__ lev_p, const int* __restrict__ meta,
                             int* __restrict__ lstart, int* __restrict__ ktab) {
    int tid = threadIdx.x;
    int maxlev = meta[0];
    if (tid < 72) {  // lstart[l] = first sorted pos with level >= l
        int lo = 0, hi = NR;
        while (lo < hi) { int mid = (lo + hi) >> 1; if (lev_p[mid] < tid) lo = mid + 1; else hi = mid; }
        lstart[tid] = lo;
    }
    __syncthreads();
    if (tid == 0) {
        int bestK = -1, bestCost = 1 << 30, bestNR = 0;
        if (maxlev <= 62) {
            int kmax = (maxlev + 1 < 16) ? (maxlev + 1) : 16;
            for (int K = 1; K <= kmax; K++) {
                int nr = 0;
                for (int l = K; l <= maxlev; l++) {
                    int n = lstart[l + 1] - lstart[l];
                    nr += (n + 63) >> 6;
                }
                if (nr > ROUNDS_MAX) continue;
                int cost = (K + 1) * 7 + nr;   // phase:round cost ratio ~7:1
                if (cost < bestCost) { bestCost = cost; bestK = K; bestNR = nr; }
            }
        }
        if (bestK < 0) { bestK = maxlev + 1; bestNR = 0; }  // pure-bulk fallback
        ktab[0] = bestK; ktab[1] = bestNR;
        int r = 0;
        for (int l = bestK; l <= maxlev && bestNR > 0; l++) {
            int s = lstart[l], n = lstart[l + 1] - s;
            while (n > 0) {
                int c = (n < 64) ? n : 64;
                ktab[2 + 2 * r] = s; ktab[3 + 2 * r] = c;
                s += c; n -= c; r++;
            }
        }
    }
}

// ---------------- q pre-permute: qperm[t][pos] = qp[t][perm[pos]] ----------------
__global__ void qperm_kernel(const float* __restrict__ qp, const int* __restrict__ perm,
                             float* __restrict__ qperm) {
    int i = blockIdx.x * 256 + threadIdx.x;
    int t = blockIdx.y;
    if (i < NR) qperm[(size_t)t * NR + i] = qp[(size_t)t * NR + perm[i]];
}

// ---------------- main routing scan ----------------
// Bulk levels 0..K-1: block-barrier phases (dependency-closed).
// Tail levels K..maxlev: single wave (15), sequential <=64-row rounds,
// in-wave LDS ordering, no block barriers. Barriers/timestep = K+1.
// Semantics: buffers hold UNCLAMPED solve results; clamp at consumption
// (prev reads, own-state term, gage output) — matches the reference.
template <bool QPERM>
__global__ __launch_bounds__(1024, 1) void route_kernel(
    const float* __restrict__ qp, const float* __restrict__ qperm,
    const float* __restrict__ c1g, const float* __restrict__ c2g,
    const float* __restrict__ c3g, const float* __restrict__ c4g,
    const int* __restrict__ rowptr_p, const int* __restrict__ cols_p,
    const int* __restrict__ lev_p, const int* __restrict__ perm,
    const int* __restrict__ meta, const int* __restrict__ ktab,
    float* __restrict__ out) {
    __shared__ float sbuf[2 * NR];     // parity ping-pong (no pointer swap)
    __shared__ float q_lds[NR];        // q row (t-1) staged for tail
    __shared__ int tl_pos[TAILCAP], tl_en[TAILCAP], tl_e0[TAILCAP];
    __shared__ int tl_col0[TAILCAP], tl_col1[TAILCAP], tl_col2[TAILCAP];
    __shared__ int tl_col3[TAILCAP], tl_col4[TAILCAP], tl_col5[TAILCAP];
    __shared__ float tl_w1[TAILCAP], tl_w2[TAILCAP], tl_w3[TAILCAP], tl_w4[TAILCAP];

    int tid = threadIdx.x;
    int gpos = meta[1];
    int K = ktab[0], nrounds = ktab[1];

    // ---- fill tail tables ----
    for (int slot = tid; slot < nrounds * 64; slot += 1024) {
        int r = slot >> 6, L = slot & 63;
        int rs = ktab[2 + 2 * r], rc = ktab[3 + 2 * r];
        int pos = (L < rc) ? rs + L : -1;
        tl_pos[slot] = pos;
        int n = 0, b0 = 0;
        if (pos >= 0) { b0 = rowptr_p[pos]; n = rowptr_p[pos + 1] - b0; }
        tl_en[slot] = n; tl_e0[slot] = b0;
        tl_col0[slot] = (n > 0) ? cols_p[b0 + 0] : 0;
        tl_col1[slot] = (n > 1) ? cols_p[b0 + 1] : 0;
        tl_col2[slot] = (n > 2) ? cols_p[b0 + 2] : 0;
        tl_col3[slot] = (n > 3) ? cols_p[b0 + 3] : 0;
        tl_col4[slot] = (n > 4) ? cols_p[b0 + 4] : 0;
        if (pos >= 0) {
            tl_col5[slot] = (n > 5) ? cols_p[b0 + 5] : 0;
            tl_w1[slot] = c1g[pos]; tl_w2[slot] = c2g[pos];
            tl_w3[slot] = c3g[pos]; tl_w4[slot] = c4g[pos];
        } else {
            tl_col5[slot] = 0;
            tl_w1[slot] = 0.f; tl_w2[slot] = 0.f; tl_w3[slot] = 0.f; tl_w4[slot] = 0.f;
        }
    }

    // ---- per-thread bulk row data (4 consecutive sorted rows) ----
    int LV[4], e0a[4], ena[4], rowg[4];
    float C1[4], C2[4], C3[4], C4[4], qreg[4];
    int colr[4][MAXC];
    int lmin = 1 << 30, lmax = -1;
#pragma unroll
    for (int k = 0; k < 4; k++) {
        int pos = tid * 4 + k;
        LV[k] = lev_p[pos];
        lmin = (LV[k] < lmin) ? LV[k] : lmin;
        lmax = (LV[k] > lmax) ? LV[k] : lmax;
        e0a[k] = rowptr_p[pos];
        ena[k] = rowptr_p[pos + 1] - e0a[k];
        C1[k] = c1g[pos]; C2[k] = c2g[pos]; C3[k] = c3g[pos]; C4[k] = c4g[pos];
        rowg[k] = perm[pos];
#pragma unroll
        for (int j = 0; j < MAXC; j++)
            colr[k][j] = (j < ena[k]) ? cols_p[e0a[k] + j] : 0;
        float v = QPERM ? qperm[pos] : qp[rowg[k]];   // x(0) = raw d0
        qreg[k] = v;                                   // q_lat for t=1
        sbuf[pos] = v;                                 // prev-buffer for t=1 (parity 0)
        if (pos == gpos) out[0] = fmaxf(v, QLB);
    }
    __syncthreads();

    for (int t = 1; t < NT; t++) {
        int curb = (t & 1) * NR;
        int prevb = curb ^ NR;
        // stage q(t-1) into LDS for tail rows (bulk uses registers directly)
#pragma unroll
        for (int k = 0; k < 4; k++) q_lds[tid * 4 + k] = qreg[k];
        // ---- bulk level phases ----
        for (int l = 0; l < K; l++) {
            if (l >= lmin && l <= lmax) {
#pragma unroll
                for (int k = 0; k < 4; k++) {
                    if (LV[k] == l) {
                        int pos = tid * 4 + k;
                        float sd = 0.f, sx = 0.f;
                        int n = ena[k];
#pragma unroll
                        for (int j = 0; j < MAXC; j++) {
                            if (j < n) {
                                int c = colr[k][j];
                                sd += fmaxf(sbuf[prevb + c], QLB);
                                sx += sbuf[curb + c];
                            }
                        }
                        for (int j = MAXC; j < n; j++) {
                            int c = cols_p[e0a[k] + j];
                            sd += fmaxf(sbuf[prevb + c], QLB);
                            sx += sbuf[curb + c];
                        }
                        float own = fmaxf(sbuf[prevb + pos], QLB);
                        float v = C2[k] * sd + C3[k] * own
                                + C4[k] * fmaxf(qreg[k], QLB) + C1[k] * sx;
                        sbuf[curb + pos] = v;                   // unclamped sol
                        if (pos == gpos) out[t] = fmaxf(v, QLB);
                    }
                }
            }
            __syncthreads();
        }
        // ---- tail: wave 15, sequential level rounds, in-wave LDS ordering ----
        if (tid >= 960) {
            int lane = tid - 960;
            for (int r = 0; r < nrounds; r++) {
                int slot = (r << 6) + lane;
                int pos = tl_pos[slot];
                if (pos >= 0) {
                    int n = tl_en[slot];
                    float sd = 0.f, sx = 0.f;
                    int cc0 = tl_col0[slot], cc1 = tl_col1[slot], cc2 = tl_col2[slot];
                    int cc3 = tl_col3[slot], cc4 = tl_col4[slot], cc5 = tl_col5[slot];
                    if (n > 0) { sd += fmaxf(sbuf[prevb + cc0], QLB); sx += sbuf[curb + cc0]; }
                    if (n > 1) { sd += fmaxf(sbuf[prevb + cc1], QLB); sx += sbuf[curb + cc1]; }
                    if (n > 2) { sd += fmaxf(sbuf[prevb + cc2], QLB); sx += sbuf[curb + cc2]; }
                    if (n > 3) { sd += fmaxf(sbuf[prevb + cc3], QLB); sx += sbuf[curb + cc3]; }
                    if (n > 4) { sd += fmaxf(sbuf[prevb + cc4], QLB); sx += sbuf[curb + cc4]; }
                    if (n > 5) { sd += fmaxf(sbuf[prevb + cc5], QLB); sx += sbuf[curb + cc5]; }
                    for (int j = MAXC; j < n; j++) {
                        int c = cols_p[tl_e0[slot] + j];
                        sd += fmaxf(sbuf[prevb + c], QLB);
                        sx += sbuf[curb + c];
                    }
                    float own = fmaxf(sbuf[prevb + pos], QLB);
                    float q = fmaxf(q_lds[pos], QLB);
                    float v = tl_w2[slot] * sd + tl_w3[slot] * own
                            + tl_w4[slot] * q + tl_w1[slot] * sx;
                    sbuf[curb + pos] = v;
                    if (pos == gpos) out[t] = fmaxf(v, QLB);
                }
            }
        }
        // prefetch q row t (for t+1): coalesced (QPERM) or gather fallback;
        // its vmcnt drain lands at the final barrier, hidden under the tail.
#pragma unroll
        for (int k = 0; k < 4; k++) {
            if (QPERM) qreg[k] = qperm[(size_t)t * NR + tid * 4 + k];
            else       qreg[k] = qp[(size_t)t * NR + rowg[k]];
        }
        __syncthreads();
    }
}

extern "C" void kernel_launch(void* const* d_in, const int* in_sizes, int n_in,
                              void* d_out, int out_size, void* d_ws, size_t ws_size,
                              hipStream_t stream) {
    const float* q_prime  = (const float*)d_in[0];
    const float* raw_n    = (const float*)d_in[1];
    const float* raw_q    = (const float*)d_in[2];
    const float* raw_p    = (const float*)d_in[3];
    const float* width    = (const float*)d_in[4];
    const float* length   = (const float*)d_in[5];
    const float* slope    = (const float*)d_in[6];
    const float* adj      = (const float*)d_in[7];
    const float* x_stor   = (const float*)d_in[8];
    float* out = (float*)d_out;

    // workspace layout (4B elems)
    float* ws_f = (float*)d_ws;
    float* c1p = ws_f;
    float* c2p = ws_f + NR;
    float* c3p = ws_f + 2 * NR;
    float* c4p = ws_f + 3 * NR;
    int* ws_i     = (int*)(ws_f + 4 * NR);
    int* cnt      = ws_i;                    // NR
    int* rowptr   = cnt + NR;                // NR+8
    int* cols     = rowptr + NR + 8;         // COLS_MAX
    int* level    = cols + COLS_MAX;         // NR
    int* perm     = level + NR;              // NR
    int* inv      = perm + NR;               // NR
    int* lev_p    = inv + NR;                // NR
    int* cnt_p    = lev_p + NR;              // NR
    int* rowptr_p = cnt_p + NR;              // NR+8
    int* cols_p   = rowptr_p + NR + 8;       // COLS_MAX
    int* meta     = cols_p + COLS_MAX;       // 8
    int* lstart   = meta + 8;                // 72
    int* ktab     = lstart + 72;             // 64
    int* endbase  = ktab + 64;

    size_t base_bytes = (size_t)((char*)endbase - (char*)d_ws);
    size_t qoff = (base_bytes + 255) & ~(size_t)255;
    size_t qbytes = (size_t)NT * NR * sizeof(float);
    bool use_qperm = (ws_size >= qoff + qbytes);
    float* qperm = (float*)((char*)d_ws + qoff);

    count_kernel<<<NR, 64, 0, stream>>>(adj, cnt);
    scan_kernel<<<1, 1024, 0, stream>>>(cnt, rowptr);
    fill_kernel<<<NR, 64, 0, stream>>>(adj, rowptr, cols);
    level_kernel<<<1, 1024, 0, stream>>>(rowptr, cols, level);
    sort_kernel<<<1, 1024, 0, stream>>>(level, cnt, perm, inv, lev_p, cnt_p, meta);
    scan_kernel<<<1, 1024, 0, stream>>>(cnt_p, rowptr_p);
    trans_kernel<<<16, 256, 0, stream>>>(perm, rowptr, cols, inv, rowptr_p, cols_p);
    coef_kernel<<<16, 256, 0, stream>>>(perm, raw_n, raw_q, raw_p, width, length,
                                        slope, x_stor, c1p, c2p, c3p, c4p);
    meta2_kernel<<<1, 128, 0, stream>>>(lev_p, meta, lstart, ktab);
    if (use_qperm) {
        dim3 g(16, NT);
        qperm_kernel<<<g, 256, 0, stream>>>(q_prime, perm, qperm);
        route_kernel<true><<<1, 1024, 0, stream>>>(q_prime, qperm, c1p, c2p, c3p, c4p,
                                                   rowptr_p, cols_p, lev_p, perm, meta,
                                                   ktab, out);
    } else {
        route_kernel<false><<<1, 1024, 0, stream>>>(q_prime, qperm, c1p, c2p, c3p, c4p,
                                                    rowptr_p, cols_p, lev_p, perm, meta,
                                                    ktab, out);
    }
}